// Round 4
// baseline (3510.871 us; speedup 1.0000x reference)
//
#include <hip/hip_runtime.h>
#include <hip/hip_bf16.h>

typedef __hip_bfloat16 bf16;
typedef unsigned short u16;
typedef unsigned int   u32;

#define PP    4096
#define HH    32
#define NTOK  32768
#define NSTEP 60
#define NOBS  10

// padded fp32 weight layout (element offsets) in ws; rows padded to 36 floats
#define OFF_WIN  0        // in_proj_w  102 x 36 (cols 34,35 = 0)
#define OFF_BIN  3672     // in_proj_b  104
#define OFF_WFSA 3776     // saw@opw    32 x 36
#define OFF_BFSA 4928     // saw@opb+sab 32
#define OFF_F2W  4960     // fc2_w      32 x 32
#define OFF_F2B  5984
#define OFF_LNG  6016
#define OFF_LNB  6048
#define WGT_FLOATS 6080
#define WGT_BYTES  (6144 * 4)

__device__ __forceinline__ float bb(bf16 v) { return __bfloat162float(v); }

// Runtime input-dtype probe on in_proj_w raw halfwords. bf16 weights
// (0.05*N(0,1)) are all |v|<1; fp32 low halfwords have random exponent bits
// (P(|v|>=1 or NaN) ~ 0.5 each) -> 40 samples, miss prob ~1e-12.
__device__ __forceinline__ int detect_f32(const u16* raw) {
  int bad = 0;
#pragma unroll
  for (int i = 0; i < 40; i++) {
    float f = __uint_as_float(((u32)raw[2 * i]) << 16);
    bad |= !(fabsf(f) < 1.0f);
  }
  return bad;
}

__device__ __forceinline__ float rdw(const void* p, int i, int f32) {
  return f32 ? ((const float*)p)[i] : bb(((const bf16*)p)[i]);
}

// Load 32 h-values for token n (fp32 or bf16 source), vectorized.
__device__ __forceinline__ void load_h(const void* hsrc, int hf32, int n, float* he) {
  if (hf32) {
    const float4* p = (const float4*)((const float*)hsrc + (size_t)n * HH);
#pragma unroll
    for (int k = 0; k < 8; k++) {
      float4 v = p[k];
      he[4 * k] = v.x; he[4 * k + 1] = v.y; he[4 * k + 2] = v.z; he[4 * k + 3] = v.w;
    }
  } else {
    const uint4* p = (const uint4*)((const bf16*)hsrc + (size_t)n * HH);
#pragma unroll
    for (int k = 0; k < 4; k++) {
      uint4 v = p[k];
      u32 w[4] = {v.x, v.y, v.z, v.w};
#pragma unroll
      for (int m = 0; m < 4; m++) {
        he[8 * k + 2 * m]     = __uint_as_float(w[m] << 16);
        he[8 * k + 2 * m + 1] = __uint_as_float(w[m] & 0xffff0000u);
      }
    }
  }
}

// outv[j] = b[rowbase+j] + W[rowbase+j] . he  for j=0..33 (fast path, padded rows)
__device__ __forceinline__ void proj34(const float* gw, int rowbase,
                                       const float* he, float* outv) {
#pragma unroll 2
  for (int j = 0; j < 34; j++) {
    const float4* w4 = (const float4*)(gw + OFF_WIN + (rowbase + j) * 36);
    float acc = gw[OFF_BIN + rowbase + j];
#pragma unroll
    for (int q4 = 0; q4 < 9; q4++) {
      float4 w = w4[q4];
      acc += w.x * he[4 * q4] + w.y * he[4 * q4 + 1]
           + w.z * he[4 * q4 + 2] + w.w * he[4 * q4 + 3];
    }
    outv[j] = acc;
  }
}

__device__ __forceinline__ void proj34_slow(const void* ipw, const void* ipb, int f32,
                                            int rowbase, const float* he, float* outv) {
  for (int j = 0; j < 34; j++) {
    float acc = rdw(ipb, rowbase + j, f32);
    for (int e = 0; e < 34; e++) acc += rdw(ipw, (rowbase + j) * 34 + e, f32) * he[e];
    outv[j] = acc;
  }
}

// One-shot weight prep into ws (fp32, padded rows, fc_sa@out_proj pre-fused):
// sa(av) = saw@(opw@av + opb) + sab == (saw@opw)@av + (saw@opb + sab)
__global__ void prep_kernel(const void* ipw, const void* ipb, const void* opw,
                            const void* opb, const void* saw, const void* sab,
                            const void* f2w, const void* f2b, const void* lng,
                            const void* lnb, float* gw) {
  const int f32 = detect_f32((const u16*)ipw);
  int i = blockIdx.x * blockDim.x + threadIdx.x;
  if (i < 3672) { int r = i / 36, e = i - r * 36;
    gw[OFF_WIN + i] = (e < 34) ? rdw(ipw, r * 34 + e, f32) : 0.f; return; }
  i -= 3672;
  if (i < 104)  { gw[OFF_BIN + i] = (i < 102) ? rdw(ipb, i, f32) : 0.f; return; }
  i -= 104;
  if (i < 1152) { int r = i / 36, e = i - r * 36; float a = 0.f;
    if (e < 34) for (int f = 0; f < 34; f++)
      a += rdw(saw, r * 34 + f, f32) * rdw(opw, f * 34 + e, f32);
    gw[OFF_WFSA + i] = a; return; }
  i -= 1152;
  if (i < 32)   { float a = rdw(sab, i, f32);
    for (int f = 0; f < 34; f++) a += rdw(saw, i * 34 + f, f32) * rdw(opb, f, f32);
    gw[OFF_BFSA + i] = a; return; }
  i -= 32;
  if (i < 1024) { gw[OFF_F2W + i] = rdw(f2w, i, f32); return; }
  i -= 1024;
  if (i < 32)   { gw[OFF_F2B + i] = rdw(f2b, i, f32); return; }
  i -= 32;
  if (i < 32)   { gw[OFF_LNG + i] = rdw(lng, i, f32); return; }
  i -= 32;
  if (i < 32)   { gw[OFF_LNB + i] = rdw(lnb, i, f32); return; }
}

// Fused step, all-fp32. Block = (batch, 2 interior patch rows).
// A1: k(4 rows) -> LDS. B1: q in regs + softmax -> w9 in regs.
// A2: v(4 rows) -> same LDS. B2: weighted sum + fused MLP + LN -> out.
__global__ __launch_bounds__(256, 1)
void step_kernel(int t, const void* x, void* out, const float* gw,
                 const void* ipw, const void* ipb, const void* opw, const void* opb,
                 const void* saw, const void* sab, const void* f2w, const void* f2b,
                 const void* lng, const void* lnb,
                 const float* hprev, float* hwrite) {
  __shared__ __align__(16) float s_kv[256 * 34];        // 34816 B, reused k then v
  __shared__ __align__(16) float s_wf[32 * 36 + 32];    // fallback fused weights

  const int f32 = detect_f32((const u16*)ipw);
  const int tt = threadIdx.x;
  const int b  = blockIdx.x >> 5;
  const int r0 = (blockIdx.x & 31) << 1;

  // h source for this step
  const void* hsrc; int hf32;
  if (t < NOBS) {
    hsrc = f32 ? (const void*)((const float*)x + (size_t)t * NTOK * HH)
               : (const void*)((const bf16*)x + (size_t)t * NTOK * HH);
    hf32 = f32;
  } else if (f32) {  // fp32 out slots are exact rolling state
    hsrc = (const void*)((const float*)out + (size_t)(t - 1) * NTOK * HH); hf32 = 1;
  } else if (hprev) {
    hsrc = hprev; hf32 = 1;
  } else {
    hsrc = (const void*)((const bf16*)out + (size_t)(t - 1) * NTOK * HH); hf32 = 0;
  }

  // Fallback: no ws -> build fused fc_sa@out_proj per block in LDS
  if (!gw) {
    for (int i = tt; i < 32 * 36 + 32; i += 256) {
      if (i < 32 * 36) {
        int r = i / 36, e = i - r * 36; float a = 0.f;
        if (e < 34) for (int f = 0; f < 34; f++)
          a += rdw(saw, r * 34 + f, f32) * rdw(opw, f * 34 + e, f32);
        s_wf[i] = a;
      } else {
        int r = i - 32 * 36; float a = rdw(sab, r, f32);
        for (int f = 0; f < 34; f++) a += rdw(saw, r * 34 + f, f32) * rdw(opb, f, f32);
        s_wf[i] = a;
      }
    }
  }

  // ---- Phase A1: token h load (kept in regs) + k projection -> LDS ----
  const int lr = tt >> 6, col = tt & 63;
  int grow = r0 - 1 + lr; grow = max(0, min(63, grow));   // slot lr holds row clamp(r0-1+lr)
  const int ntok = b * PP + grow * 64 + col;
  float he[36];
  load_h(hsrc, hf32, ntok, he);
  he[32] = grow * (1.f / 64.f); he[33] = col * (1.f / 64.f);
  he[34] = 0.f; he[35] = 0.f;

  if (gw) proj34(gw, 34, he, s_kv + tt * 34);
  else    proj34_slow(ipw, ipb, f32, 34, he, s_kv + tt * 34);
  __syncthreads();

  // ---- Phase B1: q (registers) + scores + softmax -> w9 ----
  const int active = (tt >= 64 && tt < 192);
  const int prow = r0 + lr - 1;          // valid only when active (lr in {1,2})
  const int pcol = col;
  float w9[9];
  int lts[9];
  if (active) {
    const int rr = prow + (prow == 0) - (prow == 63);   // boundary shift inward
    const int cc = pcol + (pcol == 0) - (pcol == 63);
    const int slot0 = rr - r0;                          // 0 or 1
#pragma unroll
    for (int dr = 0; dr < 3; dr++)
#pragma unroll
      for (int dc = 0; dc < 3; dc++)
        lts[dr * 3 + dc] = (slot0 + dr) * 64 + (cc - 1 + dc);

    float q[34];
    if (rr == prow && cc == pcol) {       // interior: own token is the center
      if (gw) proj34(gw, 0, he, q);
      else    proj34_slow(ipw, ipb, f32, 0, he, q);
    } else {                               // edge: reload shifted-center h
      float hq[36];
      load_h(hsrc, hf32, b * PP + rr * 64 + cc, hq);
      hq[32] = rr * (1.f / 64.f); hq[33] = cc * (1.f / 64.f);
      hq[34] = 0.f; hq[35] = 0.f;
      if (gw) proj34(gw, 0, hq, q);
      else    proj34_slow(ipw, ipb, f32, 0, hq, q);
    }

    float mx = -1e30f;
#pragma unroll
    for (int tn = 0; tn < 9; tn++) {
      const float* kp = s_kv + lts[tn] * 34;
      float d = 0.f;
#pragma unroll
      for (int e = 0; e < 34; e++) d += q[e] * kp[e];
      w9[tn] = d * 0.17149858514250882f;   // 1/sqrt(34)
      mx = fmaxf(mx, w9[tn]);
    }
    float ssum = 0.f;
#pragma unroll
    for (int tn = 0; tn < 9; tn++) { w9[tn] = expf(w9[tn] - mx); ssum += w9[tn]; }
    const float inv = 1.f / ssum;
#pragma unroll
    for (int tn = 0; tn < 9; tn++) w9[tn] *= inv;
  }
  __syncthreads();   // B1 LDS reads complete before A2 overwrite

  // ---- Phase A2: v projection -> same LDS ----
  if (gw) proj34(gw, 68, he, s_kv + tt * 34);
  else    proj34_slow(ipw, ipb, f32, 68, he, s_kv + tt * 34);
  __syncthreads();

  // ---- Phase B2: weighted sum + fused fc_sa/out_proj + residual + fc2 + LN ----
  if (active) {
    const int np = b * PP + prow * 64 + pcol;

    float av[36];
#pragma unroll
    for (int e = 0; e < 36; e++) av[e] = 0.f;
#pragma unroll
    for (int tn = 0; tn < 9; tn++) {
      const float wv = w9[tn];
      const float* vp = s_kv + lts[tn] * 34;
#pragma unroll
      for (int e = 0; e < 34; e++) av[e] += wv * vp[e];
    }

    float nh[32];
    if (gw) {
#pragma unroll 2
      for (int i2 = 0; i2 < 32; i2++) {
        const float4* w4 = (const float4*)(gw + OFF_WFSA + i2 * 36);
        float a = gw[OFF_BFSA + i2];
#pragma unroll
        for (int q4 = 0; q4 < 9; q4++) {
          float4 w = w4[q4];
          a += w.x * av[4 * q4] + w.y * av[4 * q4 + 1]
             + w.z * av[4 * q4 + 2] + w.w * av[4 * q4 + 3];
        }
        nh[i2] = he[i2] + a;
      }
    } else {
      for (int i2 = 0; i2 < 32; i2++) {
        float a = s_wf[32 * 36 + i2];
        const float* wr = s_wf + i2 * 36;
        for (int f = 0; f < 34; f++) a += wr[f] * av[f];
        nh[i2] = he[i2] + a;
      }
    }

    float y[32], m = 0.f;
    if (gw) {
#pragma unroll 2
      for (int i2 = 0; i2 < 32; i2++) {
        const float4* w4 = (const float4*)(gw + OFF_F2W + i2 * 32);
        float a = gw[OFF_F2B + i2];
#pragma unroll
        for (int q4 = 0; q4 < 8; q4++) {
          float4 w = w4[q4];
          a += w.x * nh[4 * q4] + w.y * nh[4 * q4 + 1]
             + w.z * nh[4 * q4 + 2] + w.w * nh[4 * q4 + 3];
        }
        y[i2] = a; m += a;
      }
    } else {
      for (int i2 = 0; i2 < 32; i2++) {
        float a = rdw(f2b, i2, f32);
        for (int j2 = 0; j2 < 32; j2++) a += rdw(f2w, i2 * 32 + j2, f32) * nh[j2];
        y[i2] = a; m += a;
      }
    }
    m *= (1.f / 32.f);
    float var = 0.f;
#pragma unroll
    for (int i2 = 0; i2 < 32; i2++) { float d = y[i2] - m; var += d * d; }
    var *= (1.f / 32.f);
    float rstd = rsqrtf(var + 1e-5f);
    rstd = rstd * (1.5f - 0.5f * (var + 1e-5f) * rstd * rstd);  // Newton refine

    float o[32];
#pragma unroll
    for (int i2 = 0; i2 < 32; i2++) {
      float g  = gw ? gw[OFF_LNG + i2] : rdw(lng, i2, f32);
      float b2 = gw ? gw[OFF_LNB + i2] : rdw(lnb, i2, f32);
      o[i2] = (y[i2] - m) * rstd * g + b2;
    }

    const size_t obase = ((size_t)t * NTOK + np) * HH;
    if (f32) {
      float4* po = (float4*)((float*)out + obase);
#pragma unroll
      for (int k = 0; k < 8; k++)
        po[k] = make_float4(o[4 * k], o[4 * k + 1], o[4 * k + 2], o[4 * k + 3]);
    } else {
      bf16* po = (bf16*)out + obase;
#pragma unroll
      for (int k = 0; k < 32; k++) po[k] = __float2bfloat16(o[k]);
      if (hwrite) {
        float4* ph = (float4*)(hwrite + (size_t)np * HH);
#pragma unroll
        for (int k = 0; k < 8; k++)
          ph[k] = make_float4(o[4 * k], o[4 * k + 1], o[4 * k + 2], o[4 * k + 3]);
      }
    }
  }
}

extern "C" void kernel_launch(void* const* d_in, const int* in_sizes, int n_in,
                              void* d_out, int out_size, void* d_ws, size_t ws_size,
                              hipStream_t stream) {
  const void* x = d_in[0];
  float* gw  = (ws_size >= (size_t)WGT_BYTES) ? (float*)d_ws : nullptr;
  float* hb0 = (ws_size >= (size_t)WGT_BYTES + 2ull * NTOK * HH * 4)
                 ? (float*)((char*)d_ws + WGT_BYTES) : nullptr;

  if (gw)
    prep_kernel<<<24, 256, 0, stream>>>(d_in[1], d_in[2], d_in[3], d_in[4], d_in[5],
                                        d_in[6], d_in[7], d_in[8], d_in[9], d_in[10], gw);

  for (int t = 0; t < NSTEP; t++) {
    const float* hprev = (t >= 1 && hb0) ? hb0 + (size_t)((t - 1) & 1) * NTOK * HH : nullptr;
    float*       hwr   = hb0 ? hb0 + (size_t)(t & 1) * NTOK * HH : nullptr;
    step_kernel<<<256, 256, 0, stream>>>(t, x, d_out, gw,
                                         d_in[1], d_in[2], d_in[3], d_in[4], d_in[5],
                                         d_in[6], d_in[7], d_in[8], d_in[9], d_in[10],
                                         hprev, hwr);
  }
}